// Round 6
// baseline (224.677 us; speedup 1.0000x reference)
//
#include <hip/hip_runtime.h>
#include <math.h>

#define T 32
#define K 2048
#define NBLOCKS 64
#define NTHREADS 1024
#define CPB 32                          // columns per block
#define QS (K / NTHREADS)               // 2 message slots per thread
#define LOG2PI_F 1.8378770664093453f
#define LOG_K_F  7.6246189861593985f    // log(2048)
#define SP_F     0.17677669529663687f   // sqrt(1/32)
#define LOG_SP_F (-1.7328679513998633f) // log(sqrt(1/32))

// 8-byte {value, tag} message as a single relaxed agent-scope atomic
// (bypasses non-coherent L1/L2, lands at the coherence point; the data IS
// the flag -> no release/acquire cache maintenance ever).
union Pack { float2 f; unsigned long long u; };

__device__ __forceinline__ float2 aload8(const float2* p) {
    Pack pk;
    pk.u = __hip_atomic_load((const unsigned long long*)p,
                             __ATOMIC_RELAXED, __HIP_MEMORY_SCOPE_AGENT);
    return pk.f;
}
__device__ __forceinline__ void astore8(float2* p, float v, int tag) {
    Pack pk; pk.f.x = v; pk.f.y = __int_as_float(tag);
    __hip_atomic_store((unsigned long long*)p, pk.u,
                       __ATOMIC_RELAXED, __HIP_MEMORY_SCOPE_AGENT);
}

// Fully fused dataflow chain. 64 blocks x 1024 threads; block b owns columns
// [32b, 32b+32), one wave per 2 columns. Poll fan-out = NBLOCKS*K slots/step
// (4x less than R5). Two ping-pong r buffers suffice: publishing step s+2
// requires consuming all of step s+1, which required every block to publish
// s+1, hence to have finished reading step s (poll happens before the
// block-wide barrier that precedes any publish) — no reader is ever lapped.
// Tags 1..32 never collide with the 0xAAAAAAAA workspace poison.
__global__ __launch_bounds__(NTHREADS) void fused_kernel(
    const float* __restrict__ means, const float* __restrict__ log_stds,
    const float* __restrict__ eps, float2* __restrict__ rbuf,
    float* __restrict__ out)
{
    __shared__ float2 shzr[2][K];    // 32 KB: (z_j, R_j = r_j - 16 z_j^2), parity dbuf
    __shared__ float2 lzc[T][CPB];   // own columns: (z', ct - 16 z'^2 - logK)
    __shared__ float smu[T], sstd[T];
    __shared__ float red[NTHREADS];

    const int tid  = threadIdx.x;
    const int b    = blockIdx.x;
    const int col0 = b * CPB;

    // ---- setup: thread (t = tid>>5, dcol = tid&31) handles (t, col0+dcol) ----
    {
        int t = tid >> 5, dcol = tid & 31;
        float mu = means[t];
        float st = expf(log_stds[t]);
        if (dcol == 0) { smu[t] = mu; sstd[t] = st; }
        float e = eps[t * K + col0 + dcol];
        float z = fmaf(st, e, mu);
        // (z - mu)/st == e exactly: log_q = -0.5 e^2 - log(st) - 0.5 log2pi
        float log_q = fmaf(-0.5f * e, e, -logf(st) - 0.5f * LOG2PI_F);
        float ct = -LOG_SP_F - 0.5f * LOG2PI_F - log_q;
        lzc[t][dcol] = make_float2(z, fmaf(-16.0f * z, z, ct) - LOG_K_F);
        if (t == 0) {
            float zz = z / SP_F;
            float r0 = -0.5f * zz * zz - LOG_SP_F - 0.5f * LOG2PI_F - log_q;
            astore8(&rbuf[col0 + dcol], r0, 1);   // r_0 into slot 0, tag 1
        }
    }
    __syncthreads();

    const int lane = tid & 63;
    const int wave = tid >> 6;           // 0..15: columns 2w, 2w+1

    for (int s = 0; s < T - 1; ++s) {
        const int par = s & 1;
        const float mu_s  = smu[s];
        const float std_s = sstd[s];
        const float* erow = eps + s * K;

        // ---- pre-poll: z and -16 z^2 in registers (no LDS write yet) ----
        float zloc[QS], a16[QS];
        #pragma unroll
        for (int q = 0; q < QS; ++q) {
            float e = erow[tid + q * NTHREADS];
            float z = fmaf(std_s, e, mu_s);
            zloc[q] = z;
            a16[q]  = (-16.0f * z) * z;
        }

        // ---- poll r-row: full first sweep, exec-masked retries ----
        const float2* rrow = rbuf + par * K;
        const int rtag = s + 1;
        float2 rv[QS];
        #pragma unroll
        for (int q = 0; q < QS; ++q) rv[q] = aload8(&rrow[tid + q * NTHREADS]);
        for (;;) {
            bool all = true;
            #pragma unroll
            for (int q = 0; q < QS; ++q)
                all &= (__float_as_int(rv[q].y) == rtag);
            if (all) break;
            __builtin_amdgcn_s_sleep(1);
            #pragma unroll
            for (int q = 0; q < QS; ++q)
                if (__float_as_int(rv[q].y) != rtag)
                    rv[q] = aload8(&rrow[tid + q * NTHREADS]);
        }

        // ---- stage full (z, R) pairs: single b64 write, conflict-free ----
        #pragma unroll
        for (int q = 0; q < QS; ++q)
            shzr[par][tid + q * NTHREADS] =
                make_float2(zloc[q], rv[q].x + a16[q]);
        __syncthreads();   // the only barrier this step (parity dbuf)

        // ---- pull this lane's 32-element j-chunk (b64 reads) ----
        float2 fr[32];
        #pragma unroll
        for (int it = 0; it < 32; ++it) fr[it] = shzr[par][lane + (it << 6)];

        // ---- this wave's 2 columns; max pass + recompute-exp pass ----
        float2 zc0 = lzc[s + 1][2 * wave];
        float2 zc1 = lzc[s + 1][2 * wave + 1];
        float tz0 = 32.0f * zc0.x, tz1 = 32.0f * zc1.x;
        float m0 = -INFINITY, m1 = -INFINITY;
        #pragma unroll
        for (int it = 0; it < 32; ++it) {
            // r_j - 16 (z'-z_j)^2 = (R_j + 32 z' z_j) - 16 z'^2 (const in lzc.y)
            m0 = fmaxf(m0, fmaf(tz0, fr[it].x, fr[it].y));
            m1 = fmaxf(m1, fmaf(tz1, fr[it].x, fr[it].y));
        }
        #pragma unroll
        for (int off = 32; off >= 1; off >>= 1) {
            m0 = fmaxf(m0, __shfl_xor(m0, off, 64));
            m1 = fmaxf(m1, __shfl_xor(m1, off, 64));
        }
        float s0 = 0.0f, s1 = 0.0f;
        #pragma unroll
        for (int it = 0; it < 32; ++it) {
            s0 += __expf(fmaf(tz0, fr[it].x, fr[it].y) - m0);
            s1 += __expf(fmaf(tz1, fr[it].x, fr[it].y) - m1);
        }
        #pragma unroll
        for (int off = 32; off >= 1; off >>= 1) {
            s0 += __shfl_xor(s0, off, 64);
            s1 += __shfl_xor(s1, off, 64);
        }
        if (lane < 2) {   // lane 0 -> col 2w, lane 1 -> col 2w+1
            float mm = lane ? m1 : m0;
            float sv = lane ? s1 : s0;
            float cm = lane ? zc1.y : zc0.y;
            int c = 2 * wave + lane;
            astore8(&rbuf[(par ^ 1) * K + col0 + c],
                    cm + mm + logf(sv), s + 2);
        }
        // no trailing barrier: next step uses the other LDS parity; step s+2's
        // same-parity writes are separated from step s's reads by sync #(s+1)
    }

    // ---- final logmeanexp over r_31 + likelihood, block 0 only ----
    if (b == 0) {
        const float* erow = eps + (T - 1) * K;
        const float mu_l  = smu[T - 1];
        const float std_l = sstd[T - 1];
        const float2* rrow = rbuf + ((T - 1) & 1) * K;   // parity 1, tag 32
        float ev[QS];
        #pragma unroll
        for (int q = 0; q < QS; ++q) ev[q] = erow[tid + q * NTHREADS];
        float2 rv[QS];
        #pragma unroll
        for (int q = 0; q < QS; ++q) rv[q] = aload8(&rrow[tid + q * NTHREADS]);
        for (;;) {
            bool all = true;
            #pragma unroll
            for (int q = 0; q < QS; ++q)
                all &= (__float_as_int(rv[q].y) == T);
            if (all) break;
            __builtin_amdgcn_s_sleep(1);
            #pragma unroll
            for (int q = 0; q < QS; ++q)
                if (__float_as_int(rv[q].y) != T)
                    rv[q] = aload8(&rrow[tid + q * NTHREADS]);
        }
        float vals[QS];
        float m = -INFINITY;
        #pragma unroll
        for (int q = 0; q < QS; ++q) {
            float z = fmaf(std_l, ev[q], mu_l);
            float d = 0.5f - z;
            float v = rv[q].x + fmaf(-0.5f * d, d, -0.5f * LOG2PI_F);
            vals[q] = v;
            m = fmaxf(m, v);
        }
        red[tid] = m; __syncthreads();
        for (int off = NTHREADS / 2; off >= 1; off >>= 1) {
            if (tid < off) red[tid] = fmaxf(red[tid], red[tid + off]);
            __syncthreads();
        }
        m = red[0]; __syncthreads();
        float ssum = 0.0f;
        #pragma unroll
        for (int q = 0; q < QS; ++q) ssum += __expf(vals[q] - m);
        red[tid] = ssum; __syncthreads();
        for (int off = NTHREADS / 2; off >= 1; off >>= 1) {
            if (tid < off) red[tid] += red[tid + off];
            __syncthreads();
        }
        if (tid == 0) out[0] = m + logf(red[0]) - LOG_K_F;
    }
}

extern "C" void kernel_launch(void* const* d_in, const int* in_sizes, int n_in,
                              void* d_out, int out_size, void* d_ws, size_t ws_size,
                              hipStream_t stream) {
    const float* means    = (const float*)d_in[0];
    const float* log_stds = (const float*)d_in[1];
    const float* eps      = (const float*)d_in[2];
    float* out = (float*)d_out;

    float2* rbuf = (float2*)d_ws;   // 2*K ping-pong messages {r, step-tag}

    fused_kernel<<<NBLOCKS, NTHREADS, 0, stream>>>(
        means, log_stds, eps, rbuf, out);
}